// Round 4
// baseline (1194.640 us; speedup 1.0000x reference)
//
#include <hip/hip_runtime.h>
#include <cmath>

typedef _Float16 f16;
typedef _Float16 half8 __attribute__((ext_vector_type(8)));
typedef _Float16 half4 __attribute__((ext_vector_type(4)));
typedef float f32x4 __attribute__((ext_vector_type(4)));

__device__ __forceinline__ void atomAddF(float* p, float v) { unsafeAtomicAdd(p, v); }

// async global->LDS, 16B per lane. LDS dest must be wave-uniform base + lane*16 (linear).
__device__ __forceinline__ void gload16(const void* g, void* l) {
    __builtin_amdgcn_global_load_lds((const __attribute__((address_space(1))) void*)g,
                                     (__attribute__((address_space(3))) void*)l, 16, 0, 0);
}

// ---------------- merged setup ----------------
// regions: w1t0 transpose | 6x 256x256 transposes | lin2 transpose | stats zero | deg zero
struct SetupP {
    const float* ws[7];
    f16* wd[7];
    const float* l2s;
    float* l2d;
    float* stats;  // 1536 floats (3 layers x (colsum[256], colsumsq[256]))
    int* deg;      // 136192 ints
};

__global__ void setup_all(SetupP p) {
    int i = blockIdx.x * 256 + threadIdx.x;
    if (i < 32768) {
        int k = i >> 8, n = i & 255;
        p.wd[0][(size_t)n * 128 + k] = (f16)p.ws[0][i];
        return;
    }
    i -= 32768;
    if (i < 6 * 65536) {
        int m = i >> 16, r = i & 65535;
        int k = r >> 8, n = r & 255;
        p.wd[1 + m][(size_t)n * 256 + k] = (f16)p.ws[1 + m][r];
        return;
    }
    i -= 6 * 65536;
    if (i < 12032) {
        int k = i / 47, j = i - k * 47;
        p.l2d[(size_t)j * 256 + k] = p.l2s[i];
        return;
    }
    i -= 12032;
    if (i < 1536) {
        p.stats[i] = 0.f;
        return;
    }
    i -= 1536;
    if (i < 136192) p.deg[i] = 0;
}

// ---------------- adjacency build, all 3 layers in one dispatch ----------------
__global__ void fill_all(const int* __restrict__ e0, const int* __restrict__ e1,
                         const int* __restrict__ e2, int E0, int E1, int E2, int* __restrict__ deg,
                         int* __restrict__ adj) {
    int e = blockIdx.x * 256 + threadIdx.x;
    const int *src, *tgt;
    int* d;
    int* a;
    if (e < E0) {
        src = e0; tgt = e0 + E0; d = deg; a = adj;
    } else if (e < E0 + E1) {
        e -= E0;
        src = e1; tgt = e1 + E1; d = deg + 123904; a = adj + (size_t)123904 * 64;
    } else if (e < E0 + E1 + E2) {
        e -= E0 + E1;
        src = e2; tgt = e2 + E2; d = deg + 135168; a = adj + (size_t)135168 * 64;
    } else {
        return;
    }
    int t = tgt[e];
    int pos = atomicAdd(&d[t], 1);
    if (pos < 64) a[(size_t)t * 64 + pos] = src[e];
}

// ---------------- gathers: h[t] = x[t] + sum_{s in adj[t]} x[s], one wave per row ----------------

// layer 0: x fp32 (1362944 x 128 -- full source table), h f16 (123904 x 128).
// float4 per lane, 32 lanes/row -> 2 neighbor rows per load instruction.
__global__ void gather128(const float* __restrict__ x, const int* __restrict__ deg,
                          const int* __restrict__ adj, f16* __restrict__ h) {
    const int wave = threadIdx.x >> 6, lane = threadIdx.x & 63;
    const int row = blockIdx.x * 4 + wave;
    const int hf = lane >> 5;
    const int c = (lane & 31) * 4;
    float a0 = 0.f, a1 = 0.f, a2 = 0.f, a3 = 0.f;
    if (hf == 0) {
        f32x4 v = *(const f32x4*)(x + (size_t)row * 128 + c);
        a0 = v[0]; a1 = v[1]; a2 = v[2]; a3 = v[3];
    }
    const int n = min(deg[row], 64);
    const int myadj = adj[(size_t)row * 64 + lane];
    int j = 0;
    for (; j + 4 <= n; j += 4) {
        int sA = __shfl(myadj, j + hf);
        int sB = __shfl(myadj, j + 2 + hf);
        f32x4 vA = *(const f32x4*)(x + (size_t)sA * 128 + c);
        f32x4 vB = *(const f32x4*)(x + (size_t)sB * 128 + c);
        a0 += vA[0] + vB[0];
        a1 += vA[1] + vB[1];
        a2 += vA[2] + vB[2];
        a3 += vA[3] + vB[3];
    }
    {  // tail: 0..3 remaining; half hf handles j+hf and j+2+hf (shfl executed by all lanes)
        const int i0 = j + hf, i1 = j + 2 + hf;
        int s0 = __shfl(myadj, i0 & 63);
        int s1 = __shfl(myadj, i1 & 63);
        if (i0 < n) {
            f32x4 v = *(const f32x4*)(x + (size_t)s0 * 128 + c);
            a0 += v[0]; a1 += v[1]; a2 += v[2]; a3 += v[3];
        }
        if (i1 < n) {
            f32x4 v = *(const f32x4*)(x + (size_t)s1 * 128 + c);
            a0 += v[0]; a1 += v[1]; a2 += v[2]; a3 += v[3];
        }
    }
    a0 += __shfl_xor(a0, 32);
    a1 += __shfl_xor(a1, 32);
    a2 += __shfl_xor(a2, 32);
    a3 += __shfl_xor(a3, 32);
    if (hf == 0) {
        half4 o;
        o[0] = (f16)a0;
        o[1] = (f16)a1;
        o[2] = (f16)a2;
        o[3] = (f16)a3;
        *(half4*)(h + (size_t)row * 128 + c) = o;
    }
}

__global__ void gather256(const f16* __restrict__ x, const int* __restrict__ deg,
                          const int* __restrict__ adj, f16* __restrict__ h) {
    const int wave = threadIdx.x >> 6, lane = threadIdx.x & 63;
    const int row = blockIdx.x * 4 + wave;
    const int c = lane * 4;
    half4 xv = *(const half4*)(x + (size_t)row * 256 + c);
    float a0 = (float)xv[0], a1 = (float)xv[1], a2 = (float)xv[2], a3 = (float)xv[3];
    const int n = min(deg[row], 64);
    const int myadj = adj[(size_t)row * 64 + lane];
    int j = 0;
    for (; j + 4 <= n; j += 4) {
        int s0 = __shfl(myadj, j), s1 = __shfl(myadj, j + 1);
        int s2 = __shfl(myadj, j + 2), s3 = __shfl(myadj, j + 3);
        half4 v0 = *(const half4*)(x + (size_t)s0 * 256 + c);
        half4 v1 = *(const half4*)(x + (size_t)s1 * 256 + c);
        half4 v2 = *(const half4*)(x + (size_t)s2 * 256 + c);
        half4 v3 = *(const half4*)(x + (size_t)s3 * 256 + c);
        a0 += ((float)v0[0] + (float)v1[0]) + ((float)v2[0] + (float)v3[0]);
        a1 += ((float)v0[1] + (float)v1[1]) + ((float)v2[1] + (float)v3[1]);
        a2 += ((float)v0[2] + (float)v1[2]) + ((float)v2[2] + (float)v3[2]);
        a3 += ((float)v0[3] + (float)v1[3]) + ((float)v2[3] + (float)v3[3]);
    }
    for (; j < n; ++j) {
        int s = __shfl(myadj, j);
        half4 v = *(const half4*)(x + (size_t)s * 256 + c);
        a0 += (float)v[0];
        a1 += (float)v[1];
        a2 += (float)v[2];
        a3 += (float)v[3];
    }
    half4 o;
    o[0] = (f16)a0;
    o[1] = (f16)a1;
    o[2] = (f16)a2;
    o[3] = (f16)a3;
    *(half4*)(h + (size_t)row * 256 + c) = o;
}

// ---------------- full-width gemm1: C(Mx256) = A(MxK) @ Bt^T + bias, fused col stats ----------
// BM=128, BN=256 (full), 1024 threads = 16 waves (4 row-groups x 4 col-groups), wave-tile 32x64.
// A tile read ONCE per 128 rows. global_load_lds 16B staging, chunk-XOR swizzle.
__global__ __launch_bounds__(1024) void gemmFW_stats(const f16* __restrict__ A,
                                                     const f16* __restrict__ Bt,
                                                     const float* __restrict__ bias,
                                                     f16* __restrict__ C,
                                                     float* __restrict__ colsum,
                                                     float* __restrict__ colsumsq, int M, int K) {
    __shared__ __attribute__((aligned(16))) f16 sA[128 * 32];
    __shared__ __attribute__((aligned(16))) f16 sB[256 * 32];
    __shared__ float ssum[256], ssq[256];
    const int tid = threadIdx.x;
    const int wid = tid >> 6, lane = tid & 63;
    const int quad = lane >> 4, l16 = lane & 15;
    const int wr = (wid & 3) * 32, wc = (wid >> 2) * 64;
    const int row0 = blockIdx.x * 128;

    if (tid < 256) {
        ssum[tid] = 0.f;
        ssq[tid] = 0.f;
    }

    // B staging: all 1024 threads x 16B = 16KB (rows 0..255)
    const int rb = tid >> 2, cb = (tid & 3) ^ ((rb >> 1) & 3);
    const f16* gB = Bt + (size_t)rb * K + cb * 8;
    f16* lB = &sB[tid * 8];
    // A staging: tid<512 x 16B = 8KB (rows 0..127)
    const int ia = tid & 511;
    const int ra = ia >> 2, ca = (ia & 3) ^ ((ra >> 1) & 3);
    const f16* gA = A + (size_t)(row0 + ra) * K + ca * 8;
    f16* lA = &sA[ia * 8];

    f32x4 acc[2][4] = {};

    for (int k0 = 0; k0 < K; k0 += 32) {
        __syncthreads();
        gload16(gB + k0, lB);
        if (tid < 512) gload16(gA + k0, lA);
        __syncthreads();
        half8 af[2], bf[4];
#pragma unroll
        for (int r = 0; r < 2; ++r) {
            const int ar = wr + r * 16 + l16;
            af[r] = *(const half8*)&sA[ar * 32 + ((quad ^ ((ar >> 1) & 3)) * 8)];
        }
#pragma unroll
        for (int c = 0; c < 4; ++c) {
            const int br = wc + c * 16 + l16;
            bf[c] = *(const half8*)&sB[br * 32 + ((quad ^ ((br >> 1) & 3)) * 8)];
        }
#pragma unroll
        for (int r = 0; r < 2; ++r)
#pragma unroll
            for (int c = 0; c < 4; ++c)
                acc[r][c] = __builtin_amdgcn_mfma_f32_16x16x32_f16(af[r], bf[c], acc[r][c], 0, 0, 0);
    }

    // epilogue: store + per-column stats. C/D layout: col = l16, row = quad*4 + reg.
#pragma unroll
    for (int c = 0; c < 4; ++c) {
        const int lcol = wc + c * 16 + l16;
        const float b = bias[lcol];
        float cs = 0.f, cq = 0.f;
#pragma unroll
        for (int r = 0; r < 2; ++r) {
#pragma unroll
            for (int i = 0; i < 4; ++i) {
                const int grow = row0 + wr + r * 16 + quad * 4 + i;
                float v = acc[r][c][i] + b;
                C[(size_t)grow * 256 + lcol] = (f16)v;
                cs += v;
                cq += v * v;
            }
        }
        cs += __shfl_xor(cs, 16);
        cs += __shfl_xor(cs, 32);
        cq += __shfl_xor(cq, 16);
        cq += __shfl_xor(cq, 32);
        if (quad == 0) {
            atomicAdd(&ssum[lcol], cs);
            atomicAdd(&ssq[lcol], cq);
        }
    }
    __syncthreads();
    if (tid < 256)
        atomAddF(&colsum[tid], ssum[tid]);
    else if (tid < 512)
        atomAddF(&colsumsq[tid - 256], ssq[tid - 256]);
}

// ---------------- full-width gemm2: C = relu( relu(BN(A)) @ Bt^T + bias ) ----------------
// BN scale/shift from stats (stream order); applied during A reg-staging. K=256.
__global__ __launch_bounds__(1024) void gemmFW_bn(const f16* __restrict__ A,
                                                  const f16* __restrict__ Bt,
                                                  const float* __restrict__ bias,
                                                  const float* __restrict__ colsum,
                                                  const float* __restrict__ colsumsq,
                                                  const float* __restrict__ g,
                                                  const float* __restrict__ be, float nt_inv,
                                                  f16* __restrict__ C, int M, int K) {
    __shared__ __attribute__((aligned(16))) f16 sA[128 * 32];
    __shared__ __attribute__((aligned(16))) f16 sB[256 * 32];
    __shared__ float s_scale[256], s_shift[256];
    const int tid = threadIdx.x;
    const int wid = tid >> 6, lane = tid & 63;
    const int quad = lane >> 4, l16 = lane & 15;
    const int wr = (wid & 3) * 32, wc = (wid >> 2) * 64;
    const int row0 = blockIdx.x * 128;

    if (tid < 256) {  // BN finalize, per block
        float mu = colsum[tid] * nt_inv;
        float var = colsumsq[tid] * nt_inv - mu * mu;
        float sc = g[tid] * rsqrtf(var + 1e-5f);
        s_scale[tid] = sc;
        s_shift[tid] = be[tid] - mu * sc;
    }
    __syncthreads();

    const int rb = tid >> 2, cb = (tid & 3) ^ ((rb >> 1) & 3);
    const f16* gB = Bt + (size_t)rb * K + cb * 8;
    f16* lB = &sB[tid * 8];
    const int ia = tid & 511;
    const int ra = ia >> 2, ca = (ia & 3) ^ ((ra >> 1) & 3);
    const f16* gA = A + (size_t)(row0 + ra) * K + ca * 8;
    f16* lA = &sA[ia * 8];

    f32x4 acc[2][4] = {};

    for (int k0 = 0; k0 < K; k0 += 32) {
        half8 ta;
        if (tid < 512) {  // A: load + BN+relu in registers
            half8 va = *(const half8*)(gA + k0);
            const int kb = k0 + ca * 8;
#pragma unroll
            for (int j = 0; j < 8; ++j) {
                float f = (float)va[j] * s_scale[kb + j] + s_shift[kb + j];
                ta[j] = (f16)fmaxf(f, 0.f);
            }
        }
        __syncthreads();  // prior iteration's frag reads done before overwrite
        gload16(gB + k0, lB);
        if (tid < 512) *(half8*)lA = ta;
        __syncthreads();  // drains vmcnt + lgkmcnt: tile visible
        half8 af[2], bf[4];
#pragma unroll
        for (int r = 0; r < 2; ++r) {
            const int ar = wr + r * 16 + l16;
            af[r] = *(const half8*)&sA[ar * 32 + ((quad ^ ((ar >> 1) & 3)) * 8)];
        }
#pragma unroll
        for (int c = 0; c < 4; ++c) {
            const int br = wc + c * 16 + l16;
            bf[c] = *(const half8*)&sB[br * 32 + ((quad ^ ((br >> 1) & 3)) * 8)];
        }
#pragma unroll
        for (int r = 0; r < 2; ++r)
#pragma unroll
            for (int c = 0; c < 4; ++c)
                acc[r][c] = __builtin_amdgcn_mfma_f32_16x16x32_f16(af[r], bf[c], acc[r][c], 0, 0, 0);
    }

#pragma unroll
    for (int c = 0; c < 4; ++c) {
        const int lcol = wc + c * 16 + l16;
        const float b = bias[lcol];
#pragma unroll
        for (int r = 0; r < 2; ++r) {
#pragma unroll
            for (int i = 0; i < 4; ++i) {
                const int grow = row0 + wr + r * 16 + quad * 4 + i;
                float v = fmaxf(acc[r][c][i] + b, 0.f);
                C[(size_t)grow * 256 + lcol] = (f16)v;
            }
        }
    }
}

// ---------------- 64x64 GEMM (head lin1) ----------------
template <bool RELU>
__global__ __launch_bounds__(256) void gemm_bt(const f16* __restrict__ A, const f16* __restrict__ Bt,
                                               const float* __restrict__ bias, f16* __restrict__ C,
                                               int M, int N, int K) {
    constexpr int BM = 64, BN = 64, BK = 32, LP = 40;
    __shared__ f16 sA[BM * LP];
    __shared__ f16 sB[BN * LP];
    const int tid = threadIdx.x;
    const int wave = tid >> 6, lane = tid & 63;
    const int quad = lane >> 4, l16 = lane & 15;
    const int wr = (wave & 1) * 32, wc = (wave >> 1) * 32;
    const int row0 = blockIdx.x * BM, col0 = blockIdx.y * BN;
    const int srow = tid >> 2, soff = (tid & 3) * 8;

    f32x4 acc[2][2] = {};

    for (int k0 = 0; k0 < K; k0 += BK) {
        __syncthreads();
        *(half8*)&sA[srow * LP + soff] =
            *(const half8*)(A + (size_t)(row0 + srow) * K + (k0 + soff));
        *(half8*)&sB[srow * LP + soff] =
            *(const half8*)(Bt + (size_t)(col0 + srow) * K + (k0 + soff));
        __syncthreads();
        half8 af[2], bf[2];
#pragma unroll
        for (int r = 0; r < 2; ++r) af[r] = *(const half8*)&sA[(wr + r * 16 + l16) * LP + quad * 8];
#pragma unroll
        for (int c = 0; c < 2; ++c) bf[c] = *(const half8*)&sB[(wc + c * 16 + l16) * LP + quad * 8];
#pragma unroll
        for (int r = 0; r < 2; ++r)
#pragma unroll
            for (int c = 0; c < 2; ++c)
                acc[r][c] = __builtin_amdgcn_mfma_f32_16x16x32_f16(af[r], bf[c], acc[r][c], 0, 0, 0);
    }

#pragma unroll
    for (int c = 0; c < 2; ++c) {
        const int gcol = col0 + wc + c * 16 + l16;
        const float b = bias[gcol];
#pragma unroll
        for (int r = 0; r < 2; ++r) {
#pragma unroll
            for (int i = 0; i < 4; ++i) {
                const int grow = row0 + wr + r * 16 + quad * 4 + i;
                float v = acc[r][c][i] + b;
                if (RELU) v = fmaxf(v, 0.f);
                C[(size_t)grow * N + gcol] = (f16)v;
            }
        }
    }
}

// ---------------- head: logits + log_softmax ----------------
__global__ void head2(const f16* __restrict__ T, const float* __restrict__ w2t,
                      const float* __restrict__ b2, float* __restrict__ out, int rows) {
    const int row = blockIdx.x;
    const int lane = threadIdx.x;
    __shared__ float tr[256];
    for (int i = lane; i < 256; i += 64) tr[i] = (float)T[(size_t)row * 256 + i];
    __syncthreads();
    float d = -1e30f;
    if (lane < 47) {
        const float* wr = w2t + (size_t)lane * 256;
        float dot = 0.f;
        for (int k = 0; k < 256; k += 4) {
            dot += tr[k] * wr[k] + tr[k + 1] * wr[k + 1] + tr[k + 2] * wr[k + 2] +
                   tr[k + 3] * wr[k + 3];
        }
        d = dot + b2[lane];
    }
    float m = d;
    for (int off = 32; off; off >>= 1) m = fmaxf(m, __shfl_xor(m, off));
    float e = (lane < 47) ? expf(d - m) : 0.f;
    float s = e;
    for (int off = 32; off; off >>= 1) s += __shfl_xor(s, off);
    if (lane < 47) out[(size_t)row * 47 + lane] = d - m - logf(s);
}

// ---------------- launch ----------------

extern "C" void kernel_launch(void* const* d_in, const int* in_sizes, int n_in, void* d_out,
                              int out_size, void* d_ws, size_t ws_size, hipStream_t stream) {
    const float* x0 = (const float*)d_in[0];
    const int* ei[3] = {(const int*)d_in[1], (const int*)d_in[2], (const int*)d_in[3]};
    const int E[3] = {in_sizes[1] / 2, in_sizes[2] / 2, in_sizes[3] / 2};
    const float* c_w1[3] = {(const float*)d_in[4], (const float*)d_in[10], (const float*)d_in[16]};
    const float* c_b1[3] = {(const float*)d_in[5], (const float*)d_in[11], (const float*)d_in[17]};
    const float* c_g[3] = {(const float*)d_in[6], (const float*)d_in[12], (const float*)d_in[18]};
    const float* c_be[3] = {(const float*)d_in[7], (const float*)d_in[13], (const float*)d_in[19]};
    const float* c_w2[3] = {(const float*)d_in[8], (const float*)d_in[14], (const float*)d_in[20]};
    const float* c_b2[3] = {(const float*)d_in[9], (const float*)d_in[15], (const float*)d_in[21]};
    const float* lin1_w = (const float*)d_in[22];
    const float* lin1_b = (const float*)d_in[23];
    const float* lin2_w = (const float*)d_in[24];
    const float* lin2_b = (const float*)d_in[25];
    float* out = (float*)d_out;

    const int NT[3] = {123904, 11264, 1024};

    char* base = (char*)d_ws;
    size_t off = 0;
    auto take = [&](size_t bytes) -> char* {
        char* p = base + off;
        off = (off + bytes + 255) & ~(size_t)255;
        return p;
    };
    f16* w1t[3];
    w1t[0] = (f16*)take((size_t)256 * 128 * sizeof(f16));
    w1t[1] = (f16*)take((size_t)256 * 256 * sizeof(f16));
    w1t[2] = (f16*)take((size_t)256 * 256 * sizeof(f16));
    f16* w2t[3];
    for (int i = 0; i < 3; ++i) w2t[i] = (f16*)take((size_t)256 * 256 * sizeof(f16));
    f16* lin1t = (f16*)take((size_t)256 * 256 * sizeof(f16));
    float* lin2t_ = (float*)take((size_t)47 * 256 * sizeof(float));
    float* stats = (float*)take(3 * 512 * sizeof(float));
    int* deg = (int*)take((size_t)136192 * sizeof(int));
    int* adj = (int*)take((size_t)136192 * 64 * sizeof(int));
    f16* h0 = (f16*)take((size_t)123904 * 128 * sizeof(f16));  // also holds 11264x256, 1024x256
    f16* h1 = (f16*)take((size_t)123904 * 256 * sizeof(f16));
    f16* X1 = (f16*)take((size_t)123904 * 256 * sizeof(f16));
    f16* X2 = (f16*)take((size_t)11264 * 256 * sizeof(f16));
    f16* X3 = (f16*)take((size_t)1024 * 256 * sizeof(f16));
    f16* T = (f16*)take((size_t)1024 * 256 * sizeof(f16));
    (void)ws_size;
    (void)out_size;
    (void)n_in;

    int* deg_l[3] = {deg, deg + 123904, deg + 135168};
    int* adj_l[3] = {adj, adj + (size_t)123904 * 64, adj + (size_t)135168 * 64};
    float* cs_l[3] = {stats, stats + 512, stats + 1024};  // colsum[256] | colsumsq[256]

    // merged setup (575744 work items = 2249 blocks)
    SetupP sp;
    sp.ws[0] = c_w1[0];
    sp.ws[1] = c_w1[1];
    sp.ws[2] = c_w1[2];
    sp.ws[3] = c_w2[0];
    sp.ws[4] = c_w2[1];
    sp.ws[5] = c_w2[2];
    sp.ws[6] = lin1_w;
    sp.wd[0] = w1t[0];
    sp.wd[1] = w1t[1];
    sp.wd[2] = w1t[2];
    sp.wd[3] = w2t[0];
    sp.wd[4] = w2t[1];
    sp.wd[5] = w2t[2];
    sp.wd[6] = lin1t;
    sp.l2s = lin2_w;
    sp.l2d = lin2t_;
    sp.stats = stats;
    sp.deg = deg;
    setup_all<<<2249, 256, 0, stream>>>(sp);

    fill_all<<<(E[0] + E[1] + E[2] + 255) / 256, 256, 0, stream>>>(ei[0], ei[1], ei[2], E[0], E[1],
                                                                  E[2], deg, adj);

    // ---- layer 0 (din=128; x0 is 1362944x128 fp32 -- sources span the FULL table) ----
    gather128<<<NT[0] / 4, 256, 0, stream>>>(x0, deg_l[0], adj_l[0], h0);
    gemmFW_stats<<<NT[0] / 128, 1024, 0, stream>>>(h0, w1t[0], c_b1[0], h1, cs_l[0], cs_l[0] + 256,
                                                   NT[0], 128);
    gemmFW_bn<<<NT[0] / 128, 1024, 0, stream>>>(h1, w2t[0], c_b2[0], cs_l[0], cs_l[0] + 256,
                                                c_g[0], c_be[0], 1.0f / NT[0], X1, NT[0], 256);

    // ---- layer 1 (din=256) ----
    gather256<<<NT[1] / 4, 256, 0, stream>>>(X1, deg_l[1], adj_l[1], h0);
    gemmFW_stats<<<NT[1] / 128, 1024, 0, stream>>>(h0, w1t[1], c_b1[1], h1, cs_l[1], cs_l[1] + 256,
                                                   NT[1], 256);
    gemmFW_bn<<<NT[1] / 128, 1024, 0, stream>>>(h1, w2t[1], c_b2[1], cs_l[1], cs_l[1] + 256,
                                                c_g[1], c_be[1], 1.0f / NT[1], X2, NT[1], 256);

    // ---- layer 2 (din=256) ----
    gather256<<<NT[2] / 4, 256, 0, stream>>>(X2, deg_l[2], adj_l[2], h0);
    gemmFW_stats<<<NT[2] / 128, 1024, 0, stream>>>(h0, w1t[2], c_b1[2], h1, cs_l[2], cs_l[2] + 256,
                                                   NT[2], 256);
    gemmFW_bn<<<NT[2] / 128, 1024, 0, stream>>>(h1, w2t[2], c_b2[2], cs_l[2], cs_l[2] + 256,
                                                c_g[2], c_be[2], 1.0f / NT[2], X3, NT[2], 256);

    // ---- head ----
    gemm_bt<true><<<dim3(16, 4), 256, 0, stream>>>(X3, lin1t, lin1_b, T, 1024, 256, 256);
    head2<<<1024, 64, 0, stream>>>(T, lin2t_, lin2_b, out, 1024);
}